// Round 6
// baseline (215.900 us; speedup 1.0000x reference)
//
#include <hip/hip_runtime.h>

typedef __attribute__((ext_vector_type(8))) short bf16x8;
typedef __attribute__((ext_vector_type(4))) float f32x4;
typedef unsigned short u16;

#define NN 8192
#define FD 256

__device__ __forceinline__ u16 f2bf(float f) {
  union { float f; unsigned u; } v; v.f = f;
  unsigned r = v.u + 0x7FFF + ((v.u >> 16) & 1);
  return (u16)(r >> 16);
}

// load 8 consecutive f32 and round to a bf16x8 fragment
__device__ __forceinline__ bf16x8 ldcvt8(const float* __restrict__ p) {
  f32x4 x0 = *(const f32x4*)p;
  f32x4 x1 = *(const f32x4*)(p + 4);
  bf16x8 t;
  t[0] = (short)f2bf(x0[0]); t[1] = (short)f2bf(x0[1]);
  t[2] = (short)f2bf(x0[2]); t[3] = (short)f2bf(x0[3]);
  t[4] = (short)f2bf(x1[0]); t[5] = (short)f2bf(x1[1]);
  t[6] = (short)f2bf(x1[2]); t[7] = (short)f2bf(x1[3]);
  return t;
}

// ---- K0: zero hp/lg/src/dst (replaces rocclr fillBuffer) ----
__global__ __launch_bounds__(256) void k_zero(float* __restrict__ p) {
  size_t g = (size_t)(blockIdx.x * 256 + threadIdx.x) * 4;
  f32x4 z = {0.f, 0.f, 0.f, 0.f};
  *(f32x4*)(p + g) = z;
}

// ---- K1: Wh = h @ W -> whT[c][r] (bf16), fused src/dst partial dot + atomicAdd ----
__global__ __launch_bounds__(256) void k_wh(const float* __restrict__ h,
                                            const float* __restrict__ W,
                                            const float* __restrict__ a,
                                            u16* __restrict__ whT,
                                            float* __restrict__ src,
                                            float* __restrict__ dst) {
  int tid = threadIdx.x;
  int lane = tid & 63;
  int wv = tid >> 6;
  int r0 = blockIdx.x * 64 + (wv >> 1) * 32;
  int c0 = blockIdx.y * 64 + (wv & 1) * 32;
  int lr = lane & 15;
  int q = lane >> 4;

  f32x4 acc[2][2] = {};
  for (int kk = 0; kk < FD; kk += 32) {
    int kb = kk + q * 8;
    bf16x8 av[2], bv[2];
#pragma unroll
    for (int m = 0; m < 2; m++)
      av[m] = ldcvt8(h + (size_t)(r0 + m * 16 + lr) * FD + kb);
#pragma unroll
    for (int n = 0; n < 2; n++) {
      int col = c0 + n * 16 + lr;
      const float* p = W + (size_t)kb * FD + col;
      bf16x8 t;
#pragma unroll
      for (int e = 0; e < 8; e++) t[e] = (short)f2bf(p[(size_t)e * FD]);
      bv[n] = t;
    }
#pragma unroll
    for (int m = 0; m < 2; m++)
#pragma unroll
      for (int n = 0; n < 2; n++)
        acc[m][n] = __builtin_amdgcn_mfma_f32_16x16x32_bf16(av[m], bv[n], acc[m][n], 0, 0, 0);
  }
#pragma unroll
  for (int m = 0; m < 2; m++)
#pragma unroll
    for (int n = 0; n < 2; n++) {
      int gc = c0 + n * 16 + lr;
      int gr = r0 + m * 16 + q * 4;
      ushort4 st;
      st.x = f2bf(acc[m][n][0]);
      st.y = f2bf(acc[m][n][1]);
      st.z = f2bf(acc[m][n][2]);
      st.w = f2bf(acc[m][n][3]);
      *(ushort4*)(whT + (size_t)gc * NN + gr) = st;
    }
  float aA0 = a[c0 + lr], aA1 = a[c0 + 16 + lr];
  float aB0 = a[256 + c0 + lr], aB1 = a[256 + c0 + 16 + lr];
#pragma unroll
  for (int m = 0; m < 2; m++)
#pragma unroll
    for (int j = 0; j < 4; j++) {
      float s1 = acc[m][0][j] * aA0 + acc[m][1][j] * aA1;
      float s2 = acc[m][0][j] * aB0 + acc[m][1][j] * aB1;
#pragma unroll
      for (int sh = 1; sh < 16; sh <<= 1) {
        s1 += __shfl_xor(s1, sh);
        s2 += __shfl_xor(s2, sh);
      }
      if (lr == 0) {
        int row = r0 + m * 16 + q * 4 + j;
        atomicAdd(&src[row], s1);
        atomicAdd(&dst[row], s2);
      }
    }
}

// ---- K2: attention, BM=64 rows/block, JS=4 j-quarters, 2 blocks/CU ----
// 512 blocks x 512 thr. XCD = bid%8 -> jh = bid&3 constant per XCD: the 1 MB
// whT j-slice stays L2-resident. 32 steps of 64 j. P in LDS [64][64] bf16
// XOR-swizzled, triple-buffered; lgkm-only barrier keeps the adj/whT vmcnt
// prefetch queue alive across steps. Wave w stages j-slab w (jg==w).
__global__ __launch_bounds__(512, 4) void k_att(const float* __restrict__ adj,
                                                const u16* __restrict__ whT,
                                                const float* __restrict__ src,
                                                const float* __restrict__ dst,
                                                float* __restrict__ hp,
                                                float* __restrict__ lg) {
  __shared__ u16 pbuf[3][4096];     // 3 x 8 KB
  __shared__ float dst_lds[2048];   // 8 KB
  __shared__ float lred[8][64];     // 2 KB

  const int tid = threadIdx.x;
  const int lane = tid & 63;
  const int w = tid >> 6;           // wave = j-slab for staging, col-group for MFMA
  const int lr = lane & 15;
  const int q = lane >> 4;
  const int bid = blockIdx.x;
  const int jh = bid & 3;
  const int i0 = (bid >> 2) * 64;
  const int jb = jh * 2048;

  const int pi = lane;              // P row (0..63)
  const float* adjP = adj + (size_t)(i0 + pi) * NN + jb + w * 8;
  const float srcv = src[i0 + pi];
  const int c0 = w * 32;
  const u16* wp = whT + (size_t)(c0 + lr) * NN + jb + q * 8;
  const int pw = (pi * 64 + w * 8) ^ ((pi & 7) << 3);

  f32x4 ar0[2], ar1[2];
  bf16x8 B0[2][2], B1[2][2];
  f32x4 acc[4][2] = {};
  float lsum = 0.f;

  *(f32x4*)&dst_lds[tid * 4] = *(const f32x4*)(dst + jb + tid * 4);

#define AL(S, AR)                                                              \
  { AR[0] = *(const f32x4*)(adjP + (size_t)(S) * 64);                          \
    AR[1] = *(const f32x4*)(adjP + (size_t)(S) * 64 + 4); }
#define BL(S, B)                                                               \
  { _Pragma("unroll") for (int kh = 0; kh < 2; kh++)                           \
    _Pragma("unroll") for (int n = 0; n < 2; n++)                              \
      B[kh][n] = *(const bf16x8*)(wp + (size_t)n * 16 * NN + (S) * 64 + kh * 32); }
#define PS(S, AR, WB)                                                          \
  {                                                                            \
    bf16x8 s0;                                                                 \
    _Pragma("unroll") for (int v = 0; v < 2; v++)                              \
      _Pragma("unroll") for (int e = 0; e < 4; e++) {                          \
        float x = srcv + dst_lds[(S) * 64 + w * 8 + v * 4 + e];                \
        x = fmaxf(x, 0.2f * x);                                                \
        float p = AR[v][e] * __expf(x);                                        \
        lsum += p;                                                             \
        s0[v * 4 + e] = (short)f2bf(p);                                        \
      }                                                                        \
    *(bf16x8*)&pbuf[WB][pw] = s0;                                              \
  }
#define CMPS(RB, B)                                                            \
  {                                                                            \
    _Pragma("unroll") for (int m = 0; m < 4; m++)                              \
      _Pragma("unroll") for (int kh = 0; kh < 2; kh++) {                       \
        bf16x8 pf = *(const bf16x8*)&pbuf[RB][((m * 16 + lr) * 64 + kh * 32 + q * 8) ^ ((lr & 7) << 3)]; \
        acc[m][0] = __builtin_amdgcn_mfma_f32_16x16x32_bf16(pf, B[kh][0], acc[m][0], 0, 0, 0); \
        acc[m][1] = __builtin_amdgcn_mfma_f32_16x16x32_bf16(pf, B[kh][1], acc[m][1], 0, 0, 0); \
      }                                                                        \
  }
#define LBAR asm volatile("s_waitcnt lgkmcnt(0)\n\ts_barrier" ::: "memory")

  AL(0, ar0);
  AL(1, ar1);
  BL(0, B0);
  __syncthreads();   // dst_lds ready
  PS(0, ar0, 0);
  LBAR;

  int rb = 0, wb = 1;
  for (int t = 0; t < 32; t += 2) {
    if (t + 2 < 32) AL(t + 2, ar0);
    PS(t + 1, ar1, wb);
    BL(t + 1, B1);
    CMPS(rb, B0);
    LBAR;
    rb = wb; wb = (wb == 2) ? 0 : wb + 1;
    if (t + 3 < 32) AL(t + 3, ar1);
    if (t + 2 < 32) {
      PS(t + 2, ar0, wb);
      BL(t + 2, B0);
    }
    CMPS(rb, B1);
    LBAR;
    rb = wb; wb = (wb == 2) ? 0 : wb + 1;
  }
#undef AL
#undef BL
#undef PS
#undef CMPS
#undef LBAR

  lred[w][pi] = lsum;
  __syncthreads();
  if (tid < 64) {
    float l = 0.f;
#pragma unroll
    for (int v = 0; v < 8; v++) l += lred[v][tid];
    atomicAdd(&lg[i0 + tid], l);
  }
#pragma unroll
  for (int m = 0; m < 4; m++)
#pragma unroll
    for (int n = 0; n < 2; n++)
#pragma unroll
      for (int j = 0; j < 4; j++)
        atomicAdd(&hp[(size_t)(i0 + m * 16 + q * 4 + j) * FD + c0 + n * 16 + lr],
                  acc[m][n][j]);
}

// ---- K3: normalize hp by row-sum, cast to bf16 (hpb aliases whT region) ----
__global__ __launch_bounds__(256) void k_norm(const float* __restrict__ hp,
                                              const float* __restrict__ lg,
                                              u16* __restrict__ hpb) {
  int g = blockIdx.x * 1024 + threadIdx.x * 4;
  f32x4 v = *(const f32x4*)(hp + g);
  float inv = 1.0f / lg[g >> 8];
  ushort4 st;
  st.x = f2bf(v[0] * inv);
  st.y = f2bf(v[1] * inv);
  st.z = f2bf(v[2] * inv);
  st.w = f2bf(v[3] * inv);
  *(ushort4*)(hpb + g) = st;
}

// ---- K4: fused GRUCell (h, w_ih, w_hh cast f32->bf16 inline) ----
__global__ __launch_bounds__(256) void k_gru(const u16* __restrict__ hpb,
                                             const float* __restrict__ h,
                                             const float* __restrict__ wih,
                                             const float* __restrict__ whh,
                                             const float* __restrict__ bih,
                                             const float* __restrict__ bhh,
                                             float* __restrict__ out) {
  int tid = threadIdx.x;
  int lane = tid & 63;
  int wv = tid >> 6;
  int i0 = blockIdx.x * 32;
  int lr = lane & 15;
  int q = lane >> 4;
  int c = blockIdx.y * 64 + wv * 16 + lr;
  f32x4 gi[3][2] = {};
  f32x4 gh[3][2] = {};
  for (int kk = 0; kk < FD; kk += 32) {
    int kb = kk + q * 8;
    bf16x8 ap[2], ah[2], bi[3], bh[3];
#pragma unroll
    for (int m = 0; m < 2; m++) {
      ap[m] = *(const bf16x8*)(hpb + (size_t)(i0 + m * 16 + lr) * FD + kb);
      ah[m] = ldcvt8(h + (size_t)(i0 + m * 16 + lr) * FD + kb);
    }
#pragma unroll
    for (int g = 0; g < 3; g++) {
      bi[g] = ldcvt8(wih + (size_t)(g * 256 + c) * FD + kb);
      bh[g] = ldcvt8(whh + (size_t)(g * 256 + c) * FD + kb);
    }
#pragma unroll
    for (int g = 0; g < 3; g++)
#pragma unroll
      for (int m = 0; m < 2; m++) {
        gi[g][m] = __builtin_amdgcn_mfma_f32_16x16x32_bf16(ap[m], bi[g], gi[g][m], 0, 0, 0);
        gh[g][m] = __builtin_amdgcn_mfma_f32_16x16x32_bf16(ah[m], bh[g], gh[g][m], 0, 0, 0);
      }
  }
  float bir = bih[c], biz = bih[256 + c], bin = bih[512 + c];
  float bhr = bhh[c], bhz = bhh[256 + c], bhn = bhh[512 + c];
#pragma unroll
  for (int m = 0; m < 2; m++)
#pragma unroll
    for (int j = 0; j < 4; j++) {
      int row = i0 + m * 16 + q * 4 + j;
      float rv = gi[0][m][j] + bir + gh[0][m][j] + bhr;
      float zv = gi[1][m][j] + biz + gh[1][m][j] + bhz;
      float r = 1.f / (1.f + __expf(-rv));
      float z = 1.f / (1.f + __expf(-zv));
      float nx = gi[2][m][j] + bin + r * (gh[2][m][j] + bhn);
      float n = 1.f - 2.f / (__expf(2.f * nx) + 1.f);
      float hv = h[(size_t)row * FD + c];
      out[(size_t)row * FD + c] = (1.f - z) * n + z * hv;
    }
}

extern "C" void kernel_launch(void* const* d_in, const int* in_sizes, int n_in,
                              void* d_out, int out_size, void* d_ws, size_t ws_size,
                              hipStream_t stream) {
  const float* h   = (const float*)d_in[0];
  const float* adj = (const float*)d_in[1];
  const float* W   = (const float*)d_in[2];
  const float* a   = (const float*)d_in[3];
  const float* wih = (const float*)d_in[4];
  const float* whh = (const float*)d_in[5];
  const float* bih = (const float*)d_in[6];
  const float* bhh = (const float*)d_in[7];
  float* out = (float*)d_out;

  // Workspace layout (12.68 MB total — within the proven-safe footprint):
  char* ws = (char*)d_ws;
  u16* whT   = (u16*)(ws);                  // [0, 4 MB)   Wh^T bf16; reused as hpb after k_att
  u16* hpb   = (u16*)(ws);                  //   alias — written by k_norm, read by k_gru
  float* hp  = (float*)(ws + 4194304);      // [4 MB, 12 MB) h' f32 accumulators
  float* lg  = (float*)(ws + 12582912);     // 32 KB row sums
  float* srcv = (float*)(ws + 12615680);    // 32 KB
  float* dstv = (float*)(ws + 12648448);    // 32 KB  -> end 12681216
  (void)ws_size;

  k_zero<<<2072, 256, 0, stream>>>((float*)(ws + 4194304));  // hp+lg+src+dst (8.49 MB)
  k_wh<<<dim3(128, 4), 256, 0, stream>>>(h, W, a, whT, srcv, dstv);
  k_att<<<512, 512, 0, stream>>>(adj, whT, srcv, dstv, hp, lg);
  k_norm<<<2048, 256, 0, stream>>>(hp, lg, hpb);
  k_gru<<<dim3(256, 4), 256, 0, stream>>>(hpb, h, wih, whh, bih, bhh, out);
}